// Round 1
// baseline (742.320 us; speedup 1.0000x reference)
//
#include <hip/hip_runtime.h>
#include <cstdint>

// Shapes (fixed): B=4, L=512, H=8, Dk=Dv=64, dm=512
#define NB 4
#define NL 512
#define NH 8
#define ND 64
#define NDM 512

typedef __attribute__((ext_vector_type(8))) short short8;   // 8 bf16 (4 VGPRs)
typedef __attribute__((ext_vector_type(4))) float f32x4;    // MFMA accumulator

__device__ __forceinline__ unsigned short f2bf(float f){
  union { float f; unsigned u; } v; v.f = f;
  unsigned r = (v.u + 0x7fffu + ((v.u >> 16) & 1u)) >> 16;
  return (unsigned short)r;
}

__device__ __forceinline__ short8 ld8(const unsigned short* p){
  return *(const short8*)p;
}

__device__ __forceinline__ f32x4 mfma16(short8 a, short8 b, f32x4 c){
  return __builtin_amdgcn_mfma_f32_16x16x32_bf16(a, b, c, 0, 0, 0);
}

__device__ __forceinline__ float gelu_tanh(float x){
  float u = 0.7978845608028654f * (x + 0.044715f * x * x * x);
  return 0.5f * x * (1.f + tanhf(u));
}

// ---- convert q,k,v (f32) -> bf16, contiguous [3][2048][512] ----
__global__ __launch_bounds__(256) void k_cvt_in(const float* __restrict__ q,
    const float* __restrict__ k, const float* __restrict__ v,
    unsigned short* __restrict__ dst){
  int i = blockIdx.x * 256 + threadIdx.x;        // 0..786431 (float4 units)
  int w = i >> 18, r = i & 262143;
  const float* src = (w == 0) ? q : (w == 1) ? k : v;
  float4 f = *(const float4*)(src + (size_t)r * 4);
  unsigned lo = (unsigned)f2bf(f.x) | ((unsigned)f2bf(f.y) << 16);
  unsigned hi = (unsigned)f2bf(f.z) | ((unsigned)f2bf(f.w) << 16);
  uint2 o; o.x = lo; o.y = hi;
  *(uint2*)(dst + (size_t)w * 1048576 + (size_t)r * 4) = o;
}

// ---- transpose+convert 6 weights [K][N] f32 -> [N][K] bf16 ----
__global__ __launch_bounds__(256) void k_cvt_w(const float* __restrict__ wqs,
    const float* __restrict__ wks, const float* __restrict__ wvs,
    const float* __restrict__ wself, const float* __restrict__ wdd,
    const float* __restrict__ wfc, unsigned short* __restrict__ Wt){
  int i = blockIdx.x * 256 + threadIdx.x;        // 0..1572863
  int w = i >> 18, r = i & 262143;
  const float* src = (w == 0) ? wqs : (w == 1) ? wks : (w == 2) ? wvs :
                     (w == 3) ? wself : (w == 4) ? wdd : wfc;
  int kk = r >> 9, n = r & 511;                  // coalesced read, scattered write
  Wt[(size_t)w * 262144 + (size_t)n * 512 + kk] = f2bf(src[r]);
}

// ---- projection GEMM: [2048,512]@[512,512] -> permuted bf16 ----
// mode 0: qs (scale 1/8) -> [B,H,L,D]; 1: kh -> [B,H,L,D]; 2: vhT -> [B,H,D,L]
__global__ __launch_bounds__(256) void k_proj(const unsigned short* __restrict__ X,
    const unsigned short* __restrict__ W, unsigned short* __restrict__ dst, int mode){
  int wid = blockIdx.x * 4 + (threadIdx.x >> 6);
  int lane = threadIdx.x & 63;
  int tm = wid >> 5, tn = wid & 31;
  int r = lane & 15, q = lane >> 4;
  const unsigned short* A  = X + (size_t)(tm * 16 + r) * 512 + q * 8;
  const unsigned short* Bp = W + (size_t)(tn * 16 + r) * 512 + q * 8;
  f32x4 acc = {0.f, 0.f, 0.f, 0.f};
  for (int k = 0; k < 512; k += 32) acc = mfma16(ld8(A + k), ld8(Bp + k), acc);
  int col = tn * 16 + r;
  int h = col >> 6, d = col & 63;
  float sc = (mode == 0) ? 0.125f : 1.0f;
  for (int i = 0; i < 4; i++){
    int row = tm * 16 + q * 4 + i;
    int b = row >> 9, l = row & 511;
    float vv = acc[i] * sc;
    size_t idx = (mode == 2) ? ((size_t)((b * 8 + h) * 64 + d) * 512 + l)
                             : ((size_t)((b * 8 + h) * 512 + l) * 64 + d);
    dst[idx] = f2bf(vv);
  }
}

// ---- content scores: per (b,h): qs[512,64] @ kh[512,64]^T -> f32 ----
__global__ __launch_bounds__(256) void k_scores(const unsigned short* __restrict__ qs,
    const unsigned short* __restrict__ kh, float* __restrict__ attnF){
  int wid = blockIdx.x * 4 + (threadIdx.x >> 6);
  int lane = threadIdx.x & 63;
  int bh = wid >> 10, tile = wid & 1023;
  int tm = tile >> 5, tn = tile & 31;
  int r = lane & 15, q = lane >> 4;
  const unsigned short* A  = qs + (size_t)bh * 512 * 64 + (size_t)(tm * 16 + r) * 64 + q * 8;
  const unsigned short* Bp = kh + (size_t)bh * 512 * 64 + (size_t)(tn * 16 + r) * 64 + q * 8;
  f32x4 acc = {0.f, 0.f, 0.f, 0.f};
  acc = mfma16(ld8(A),      ld8(Bp),      acc);
  acc = mfma16(ld8(A + 32), ld8(Bp + 32), acc);
  float* C = attnF + (size_t)bh * 512 * 512;
  for (int i = 0; i < 4; i++){
    int row = tm * 16 + q * 4 + i;
    C[(size_t)row * 512 + tn * 16 + r] = acc[i];
  }
}

// ---- rel scores (stream vec_adj_k) + mask + softmax, per (b,l) ----
__global__ __launch_bounds__(256) void k_relsoft(const unsigned short* __restrict__ qs,
    const float* __restrict__ vak, const int* __restrict__ adj,
    float* __restrict__ attnF, unsigned short* __restrict__ attn_bf){
  int bid = blockIdx.x;
  int b = bid >> 9, l = bid & 511;
  int t = threadIdx.x, lane = t & 63, w = t >> 6;
  __shared__ __align__(16) unsigned short qsA[16 * 64];
  __shared__ __align__(16) unsigned short vkt[128 * 72];   // [m][d], stride 72
  __shared__ float sc[8 * 512];
  __shared__ int adjs[512];
  for (int j = 0; j < 4; j++){
    int e = t + j * 256;
    int m = e >> 6, d = e & 63;
    qsA[e] = (m < 8) ? qs[((size_t)((b * 8 + m) * 512 + l)) * 64 + d] : (unsigned short)0;
  }
  for (int j = 0; j < 16; j++){
    int e = t + j * 256;
    int h = e >> 9, m = e & 511;
    sc[e] = attnF[((size_t)(b * 8 + h) * 512 + l) * 512 + m];
  }
  adjs[t]       = adj[(size_t)bid * 512 + t];
  adjs[t + 256] = adj[(size_t)bid * 512 + t + 256];
  __syncthreads();
  int r = lane & 15, q = lane >> 4;
  short8 a0 = ld8(qsA + r * 64 + q * 8);
  short8 a1 = ld8(qsA + r * 64 + 32 + q * 8);
  const float* vrow = vak + (size_t)bid * 512 * 64;
  for (int c = 0; c < 4; c++){
    for (int it = 0; it < 16; it++){
      int i2 = it * 256 + t;                    // 4096 float2 per 128x64 chunk
      int m = i2 >> 5, d2 = (i2 & 31) * 2;
      const float2 f = *(const float2*)(vrow + (size_t)(c * 128 + m) * 64 + d2);
      unsigned pack = (unsigned)f2bf(f.x) | ((unsigned)f2bf(f.y) << 16);
      *(unsigned*)(&vkt[m * 72 + d2]) = pack;
    }
    __syncthreads();
    for (int nt2 = 0; nt2 < 2; nt2++){
      int nt = w * 2 + nt2;
      const unsigned short* bp = vkt + (nt * 16 + r) * 72 + q * 8;
      f32x4 acc = {0.f, 0.f, 0.f, 0.f};
      acc = mfma16(a0, ld8(bp),      acc);
      acc = mfma16(a1, ld8(bp + 32), acc);
      if (q < 2){
        for (int i = 0; i < 4; i++){
          int h = q * 4 + i;                    // rows 0..7 = heads
          sc[h * 512 + c * 128 + nt * 16 + r] += acc[i];
        }
      }
    }
    __syncthreads();
  }
  // mask + softmax: wave w handles rows 2w, 2w+1
  for (int hh = 0; hh < 2; hh++){
    int h = w * 2 + hh;
    float v[8]; float mx = -3.0e38f;
    for (int i = 0; i < 8; i++){
      int m = lane + i * 64;
      float s = sc[h * 512 + m];
      if (adjs[m] == 0) s = -10000.0f;
      v[i] = s; mx = fmaxf(mx, s);
    }
    for (int off = 32; off; off >>= 1) mx = fmaxf(mx, __shfl_xor(mx, off, 64));
    float sum = 0.f;
    for (int i = 0; i < 8; i++){ v[i] = __expf(v[i] - mx); sum += v[i]; }
    for (int off = 32; off; off >>= 1) sum += __shfl_xor(sum, off, 64);
    float inv = 1.f / sum;
    size_t base = ((size_t)(b * 8 + h) * 512 + l) * 512;
    for (int i = 0; i < 8; i++){
      int m = lane + i * 64;
      float p2 = v[i] * inv;
      attnF[base + m] = p2;
      attn_bf[base + m] = f2bf(p2);
    }
  }
}

// ---- out content: per (b,h): attn[512,512] @ vh[512,64] -> qc f32 ----
__global__ __launch_bounds__(256) void k_outc(const unsigned short* __restrict__ attn_bf,
    const unsigned short* __restrict__ vhT, float* __restrict__ qc){
  int wid = blockIdx.x * 4 + (threadIdx.x >> 6);
  int lane = threadIdx.x & 63;
  int bh = wid >> 7, tile = wid & 127;
  int tm = tile >> 2, tn = tile & 3;
  int r = lane & 15, q = lane >> 4;
  const unsigned short* A  = attn_bf + (size_t)bh * 512 * 512 + (size_t)(tm * 16 + r) * 512 + q * 8;
  const unsigned short* Bp = vhT + (size_t)bh * 64 * 512 + (size_t)(tn * 16 + r) * 512 + q * 8;
  f32x4 acc = {0.f, 0.f, 0.f, 0.f};
  for (int k = 0; k < 512; k += 32) acc = mfma16(ld8(A + k), ld8(Bp + k), acc);
  int b = bh >> 3, h = bh & 7;
  int d = tn * 16 + r;
  for (int i = 0; i < 4; i++){
    int lrow = tm * 16 + q * 4 + i;
    qc[(size_t)(b * 512 + lrow) * 512 + h * 64 + d] = acc[i];
  }
}

// ---- out rel (stream vec_adj_v) + qc finalize + node_weight + denom ----
__global__ __launch_bounds__(256) void k_outrel(const unsigned short* __restrict__ attn_bf,
    const float* __restrict__ vav, const float* __restrict__ qc,
    const int* __restrict__ adj, const float* __restrict__ wnw,
    unsigned short* __restrict__ qc_bf, float* __restrict__ nw, float* __restrict__ invden){
  int bid = blockIdx.x;
  int b = bid >> 9, l = bid & 511;
  int t = threadIdx.x, lane = t & 63, w = t >> 6;
  __shared__ __align__(16) unsigned short vvT[64 * 136];   // [d][m], stride 136
  __shared__ float orL[512];
  __shared__ float redf[4];
  __shared__ int redi[4];
  int r = lane & 15, q = lane >> 4;
  int h8 = r & 7;
  const float* vrow = vav + (size_t)bid * 512 * 64;
  const unsigned short* arow = attn_bf + ((size_t)(b * 8 + h8) * 512 + l) * 512;
  f32x4 acc = {0.f, 0.f, 0.f, 0.f};
  for (int c = 0; c < 4; c++){
    for (int it = 0; it < 16; it++){
      int i2 = it * 256 + t;
      int m = i2 >> 5, d2 = (i2 & 31) * 2;
      const float2 f = *(const float2*)(vrow + (size_t)(c * 128 + m) * 64 + d2);
      vvT[d2 * 136 + m]       = f2bf(f.x);     // transposed store
      vvT[(d2 + 1) * 136 + m] = f2bf(f.y);
    }
    __syncthreads();
    for (int s = 0; s < 4; s++){
      int kk = c * 128 + s * 32;
      short8 av = ld8(arow + kk + q * 8);
      short8 bv = ld8(vvT + (w * 16 + r) * 136 + s * 32 + q * 8);
      acc = mfma16(av, bv, acc);
    }
    __syncthreads();
  }
  if (q < 2){
    for (int i = 0; i < 4; i++){
      int h = q * 4 + i;
      orL[h * 64 + w * 16 + r] = acc[i];
    }
  }
  __syncthreads();
  float part = 0.f; int asum = 0;
  for (int j = 0; j < 2; j++){
    int e = t + j * 256;
    float val = qc[(size_t)bid * 512 + e] + orL[e];
    qc_bf[(size_t)bid * 512 + e] = f2bf(val);
    part += val * wnw[e];
    asum += adj[(size_t)bid * 512 + e];
  }
  for (int off = 32; off; off >>= 1){
    part += __shfl_xor(part, off, 64);
    asum += __shfl_xor(asum, off, 64);
  }
  if (lane == 0){ redf[w] = part; redi[w] = asum; }
  __syncthreads();
  if (t == 0){
    float tot = redf[0] + redf[1] + redf[2] + redf[3];
    int at = redi[0] + redi[1] + redi[2] + redi[3];
    nw[bid] = 1.f / (1.f + __expf(-tot));
    invden[bid] = 1.f / ((at >= 1) ? (float)at : 1.f);
  }
}

// ---- dd_weight build: ddw[b,l,m] = adj ? nw[b,m]/den[b,l] : 0 (bf16) ----
__global__ __launch_bounds__(256) void k_ddw(const int* __restrict__ adj,
    const float* __restrict__ nw, const float* __restrict__ invden,
    unsigned short* __restrict__ ddw){
  int i = blockIdx.x * 256 + threadIdx.x;      // 0..1048575
  int b = i >> 18, rest = i & 262143;
  int l = rest >> 9, m = rest & 511;
  int a = adj[i];
  float v = a ? nw[b * 512 + m] * invden[b * 512 + l] : 0.f;
  ddw[i] = f2bf(v);
}

// ---- GNN GEMM: qc_bf[2048,512]@W -> mode0: self_info f32; mode1: ddT bf16 ----
__global__ __launch_bounds__(256) void k_gnn(const unsigned short* __restrict__ qcb,
    const unsigned short* __restrict__ W, float* __restrict__ outf,
    unsigned short* __restrict__ outT, int mode){
  int wid = blockIdx.x * 4 + (threadIdx.x >> 6);
  int lane = threadIdx.x & 63;
  int tm = wid >> 5, tn = wid & 31;
  int r = lane & 15, q = lane >> 4;
  const unsigned short* A  = qcb + (size_t)(tm * 16 + r) * 512 + q * 8;
  const unsigned short* Bp = W + (size_t)(tn * 16 + r) * 512 + q * 8;
  f32x4 acc = {0.f, 0.f, 0.f, 0.f};
  for (int k = 0; k < 512; k += 32) acc = mfma16(ld8(A + k), ld8(Bp + k), acc);
  int col = tn * 16 + r;
  for (int i = 0; i < 4; i++){
    int row = tm * 16 + q * 4 + i;
    if (mode == 0) outf[(size_t)row * 512 + col] = acc[i];
    else {
      int b = row >> 9, m = row & 511;
      outT[((size_t)(b * 512 + col)) * 512 + m] = f2bf(acc[i]);  // transposed bf16
    }
  }
}

// ---- agg GEMM per b: ddw[512,512]@dd_info[512,512] + self -> xbf bf16 ----
__global__ __launch_bounds__(256) void k_agg(const unsigned short* __restrict__ ddw,
    const unsigned short* __restrict__ ddT, const float* __restrict__ selfi,
    unsigned short* __restrict__ xbf){
  int wid = blockIdx.x * 4 + (threadIdx.x >> 6);
  int lane = threadIdx.x & 63;
  int b = wid >> 10, tile = wid & 1023;
  int tm = tile >> 5, tn = tile & 31;
  int r = lane & 15, q = lane >> 4;
  const unsigned short* A  = ddw + (size_t)b * 262144 + (size_t)(tm * 16 + r) * 512 + q * 8;
  const unsigned short* Bp = ddT + (size_t)b * 262144 + (size_t)(tn * 16 + r) * 512 + q * 8;
  f32x4 acc = {0.f, 0.f, 0.f, 0.f};
  for (int k = 0; k < 512; k += 32) acc = mfma16(ld8(A + k), ld8(Bp + k), acc);
  int col = tn * 16 + r;
  for (int i = 0; i < 4; i++){
    int row = b * 512 + tm * 16 + q * 4 + i;
    float x = acc[i] + selfi[(size_t)row * 512 + col];
    xbf[(size_t)row * 512 + col] = f2bf(x);
  }
}

// ---- final: xbf@Wfc -> gelu -> + residual -> qo f32 ----
__global__ __launch_bounds__(256) void k_fc(const unsigned short* __restrict__ xbf,
    const unsigned short* __restrict__ W, const float* __restrict__ qin,
    float* __restrict__ qo){
  int wid = blockIdx.x * 4 + (threadIdx.x >> 6);
  int lane = threadIdx.x & 63;
  int tm = wid >> 5, tn = wid & 31;
  int r = lane & 15, q = lane >> 4;
  const unsigned short* A  = xbf + (size_t)(tm * 16 + r) * 512 + q * 8;
  const unsigned short* Bp = W + (size_t)(tn * 16 + r) * 512 + q * 8;
  f32x4 acc = {0.f, 0.f, 0.f, 0.f};
  for (int k = 0; k < 512; k += 32) acc = mfma16(ld8(A + k), ld8(Bp + k), acc);
  int col = tn * 16 + r;
  for (int i = 0; i < 4; i++){
    int row = tm * 16 + q * 4 + i;
    qo[(size_t)row * 512 + col] = qin[(size_t)row * 512 + col] + gelu_tanh(acc[i]);
  }
}

extern "C" void kernel_launch(void* const* d_in, const int* in_sizes, int n_in,
                              void* d_out, int out_size, void* d_ws, size_t ws_size,
                              hipStream_t stream){
  const float* q    = (const float*)d_in[0];
  const float* k    = (const float*)d_in[1];
  const float* v    = (const float*)d_in[2];
  const float* vak  = (const float*)d_in[3];
  const float* vav  = (const float*)d_in[4];
  const int*   adjk = (const int*)d_in[5];
  // d_in[6] = adj_v: unused by the reference
  const float* wqs  = (const float*)d_in[7];
  const float* wks  = (const float*)d_in[8];
  const float* wvs  = (const float*)d_in[9];
  const float* wfc  = (const float*)d_in[10];
  const float* wnw  = (const float*)d_in[11];
  const float* wself= (const float*)d_in[12];
  const float* wdd  = (const float*)d_in[13];

  float* qo    = (float*)d_out;               // [4,512,512]
  float* attnF = qo + 1048576;                // [4,8,512,512]

  char* p = (char*)d_ws;
  unsigned short* xin   = (unsigned short*)p; p += 6291456;   // q,k,v bf16
  unsigned short* Wt    = (unsigned short*)p; p += 3145728;   // 6 transposed weights bf16
  unsigned short* qsb   = (unsigned short*)p; p += 2097152;   // [B,H,L,D]
  unsigned short* khb   = (unsigned short*)p; p += 2097152;   // [B,H,L,D]
  unsigned short* vhT   = (unsigned short*)p; p += 2097152;   // [B,H,D,L]
  unsigned short* attnb = (unsigned short*)p; p += 16777216;  // [B,H,L,L] bf16
  float*          qc    = (float*)p;          p += 4194304;   // [2048,512]
  unsigned short* qcb   = (unsigned short*)p; p += 2097152;
  float*          nw    = (float*)p;          p += 8192;
  float*          invd  = (float*)p;          p += 8192;
  float*          selfi = (float*)p;          p += 4194304;
  unsigned short* ddT   = (unsigned short*)p; p += 2097152;   // [B, n, m] bf16
  unsigned short* ddw   = (unsigned short*)p; p += 2097152;   // [B, l, m] bf16
  unsigned short* xbf   = (unsigned short*)p; p += 2097152;

  k_cvt_in<<<3072, 256, 0, stream>>>(q, k, v, xin);
  k_cvt_w<<<6144, 256, 0, stream>>>(wqs, wks, wvs, wself, wdd, wfc, Wt);
  k_proj<<<1024, 256, 0, stream>>>(xin,           Wt,          qsb, 0);
  k_proj<<<1024, 256, 0, stream>>>(xin + 1048576, Wt + 262144, khb, 1);
  k_proj<<<1024, 256, 0, stream>>>(xin + 2097152, Wt + 524288, vhT, 2);
  k_scores<<<8192, 256, 0, stream>>>(qsb, khb, attnF);
  k_relsoft<<<2048, 256, 0, stream>>>(qsb, vak, adjk, attnF, attnb);
  k_outc<<<1024, 256, 0, stream>>>(attnb, vhT, qc);
  k_outrel<<<2048, 256, 0, stream>>>(attnb, vav, qc, adjk, wnw, qcb, nw, invd);
  k_ddw<<<4096, 256, 0, stream>>>(adjk, nw, invd, ddw);
  k_gnn<<<1024, 256, 0, stream>>>(qcb, Wt + 786432,  selfi, (unsigned short*)nullptr, 0);
  k_gnn<<<1024, 256, 0, stream>>>(qcb, Wt + 1048576, (float*)nullptr, ddT, 1);
  k_agg<<<1024, 256, 0, stream>>>(ddw, ddT, selfi, xbf);
  k_fc<<<1024, 256, 0, stream>>>(xbf, Wt + 1310720, q, qo);
}